// Round 5
// baseline (102.033 us; speedup 1.0000x reference)
//
#include <hip/hip_runtime.h>
#include <math.h>

#define BSZ   4096
#define NROWS 8192
#define DIM   128
#define EPSC  1e-12f
#define NRB   64              // 128-row blocks
#define NTILES 2080           // NRB*(NRB+1)/2 upper-triangle tiles

typedef _Float16 half8 __attribute__((ext_vector_type(8)));
typedef float    f32x4 __attribute__((ext_vector_type(4)));

typedef __attribute__((address_space(1))) const unsigned int gas_u32;
typedef __attribute__((address_space(3))) unsigned int       las_u32;

// Stage one 32KB tile (128 rows x 256B) linearly into LDS: 8 chunks/thread.
__device__ __forceinline__ void stageB(_Float16* lds, const char* gsrc, int w, int lane) {
    #pragma unroll
    for (int it = 0; it < 8; ++it) {
        int c = w * 8 + it;                       // 1KB chunk id, 32 per tile
        __builtin_amdgcn_global_load_lds(
            (gas_u32*)(gsrc + c * 1024 + lane * 16),
            (las_u32*)((char*)lds + c * 1024), 16, 0, 0);
    }
}

// Pass 1: view-major restack + L2 row-normalize. fp32 cf (finish pass) and one
// fp16 array in XOR-swizzled row layout (byte b -> b ^ ((row&7)<<4)); A-frags
// read it from global with XOR'd addresses, B stages linearly into LDS and
// ds_reads with the same XOR (rule #21). Zeros s[] and out[0].
__global__ __launch_bounds__(256) void norm_zero_kernel(
    const float* __restrict__ feat, float* __restrict__ cf,
    unsigned int* __restrict__ hsw, float* __restrict__ s, float* __restrict__ out)
{
    int t = blockIdx.x * 256 + threadIdx.x;
    if (t < NROWS) s[t] = 0.0f;
    if (t == 0) out[0] = 0.0f;

    int row  = t >> 6;          // one wave per row
    int lane = t & 63;
    int v = row >> 12;
    int b = row & 4095;
    const float* src = feat + (size_t)b * 256 + (size_t)v * 128;
    float2 x = *(const float2*)(src + lane * 2);
    float ss = x.x * x.x + x.y * x.y;
    #pragma unroll
    for (int m = 32; m >= 1; m >>= 1) ss += __shfl_xor(ss, m, 64);
    float inv = 1.0f / sqrtf(ss);
    float2 o; o.x = x.x * inv; o.y = x.y * inv;
    *(float2*)(cf + (size_t)row * DIM + lane * 2) = o;

    union { _Float16 h[2]; unsigned int u; } cv;
    cv.h[0] = (_Float16)o.x;
    cv.h[1] = (_Float16)o.y;
    size_t off = (size_t)row * 256 + ((lane * 4) ^ ((row & 7) << 4));
    *(unsigned int*)((char*)hsw + off) = cv.u;
}

// Pass 2: upper-triangle fp16 MFMA gram. One 128x128 tile per block (rb<=cb).
// A in registers, B single-buffered in 32KB LDS -> 2 blocks/CU. Off-diag tiles
// scatter exp-sums to BOTH row i (row-reduce) and row j (col-reduce).
__global__ __launch_bounds__(256, 2) void gram_tri_kernel(
    const _Float16* __restrict__ h, float* __restrict__ s)
{
    __shared__ _Float16 bt[128 * 128];            // 32KB

    int t    = threadIdx.x;
    int w    = t >> 6;
    int lane = t & 63;
    int r16  = lane & 15;
    int g    = lane >> 4;
    int wr   = w >> 1, wc = w & 1;
    int swz  = (r16 & 7) << 4;
    const char* hb = (const char*)h;

    // linear bid -> upper-triangle (rb, cb): offset(r) = 64r - r(r-1)/2
    int bid = blockIdx.x;
    int rb = (int)(64.5f - sqrtf(64.5f * 64.5f - 2.0f * (float)bid));
    rb = rb < 0 ? 0 : (rb > 63 ? 63 : rb);
    while (rb > 0 && 64 * rb - (rb * (rb - 1)) / 2 > bid) --rb;
    while (rb < 63 && 64 * (rb + 1) - ((rb + 1) * rb) / 2 <= bid) ++rb;
    int cb = rb + (bid - (64 * rb - (rb * (rb - 1)) / 2));
    int i0 = rb * 128, j0 = cb * 128;

    // A fragments straight into registers (issue before B staging)
    half8 A[4][4];
    #pragma unroll
    for (int f = 0; f < 4; ++f) {
        size_t rowoff = (size_t)(i0 + wr * 64 + f * 16 + r16) * 256;
        #pragma unroll
        for (int ks = 0; ks < 4; ++ks)
            A[f][ks] = *(const half8*)(hb + rowoff + ((ks * 64 + g * 16) ^ swz));
    }
    stageB(bt, hb + (size_t)j0 * 256, w, lane);
    asm volatile("s_waitcnt vmcnt(0)" ::: "memory");
    __builtin_amdgcn_s_barrier();

    f32x4 acc[4][4];
    #pragma unroll
    for (int fr = 0; fr < 4; ++fr)
        #pragma unroll
        for (int fc = 0; fc < 4; ++fc) acc[fr][fc] = (f32x4){0.f, 0.f, 0.f, 0.f};

    const char* bb = (const char*)bt;
    #pragma unroll
    for (int ks = 0; ks < 4; ++ks) {
        half8 B[4];
        #pragma unroll
        for (int fc = 0; fc < 4; ++fc)
            B[fc] = *(const half8*)(bb + (wc * 64 + fc * 16 + r16) * 256
                                       + ((ks * 64 + g * 16) ^ swz));
        #pragma unroll
        for (int fr = 0; fr < 4; ++fr)
            #pragma unroll
            for (int fc = 0; fc < 4; ++fc)
                acc[fr][fc] = __builtin_amdgcn_mfma_f32_16x16x32_f16(
                    A[fr][ks], B[fc], acc[fr][fc], 0, 0, 0);
    }

    // epilogue: e = exp(-sqrt(2-2g)) (e^1 folded into finish); accumulate
    // row partials rs[fr][q] and col partials rc[fc].
    int dw = (rb == cb) && (wr == wc);            // block/wave-uniform
    int eq[4];
    #pragma unroll
    for (int q = 0; q < 4; ++q) eq[q] = (g * 4 + q) == r16;

    float rs[4][4], rc[4] = {0.f, 0.f, 0.f, 0.f};
    #pragma unroll
    for (int fr = 0; fr < 4; ++fr)
        #pragma unroll
        for (int q = 0; q < 4; ++q) rs[fr][q] = 0.0f;

    #pragma unroll
    for (int fr = 0; fr < 4; ++fr)
        #pragma unroll
        for (int fc = 0; fc < 4; ++fc)
            #pragma unroll
            for (int q = 0; q < 4; ++q) {
                float gv = acc[fr][fc][q];
                float t2 = fmaxf(fmaf(-2.0f, gv, 2.0f), EPSC);
                float e  = __expf(-__builtin_amdgcn_sqrtf(t2));
                if (dw && (fr == fc) && eq[q]) e = 0.0f;
                rs[fr][q] += e;
                rc[fc]    += e;
            }

    // row sums: reduce over the 16 col-lanes, one atomic per row
    #pragma unroll
    for (int fr = 0; fr < 4; ++fr)
        #pragma unroll
        for (int q = 0; q < 4; ++q) {
            float v = rs[fr][q];
            v += __shfl_xor(v, 1, 64);
            v += __shfl_xor(v, 2, 64);
            v += __shfl_xor(v, 4, 64);
            v += __shfl_xor(v, 8, 64);
            if (r16 == 0)
                atomicAdd(&s[i0 + wr * 64 + fr * 16 + g * 4 + q], v);
        }

    // col sums (off-diagonal tiles): reduce over g, atomic per column
    if (rb != cb) {
        #pragma unroll
        for (int fc = 0; fc < 4; ++fc) {
            float v = rc[fc];
            v += __shfl_xor(v, 16, 64);
            v += __shfl_xor(v, 32, 64);
            if (g == 0)
                atomicAdd(&s[j0 + wc * 64 + fc * 16 + r16], v);
        }
    }
}

// Pass 3: partner dot (fp32) + loss = mean(1 + log(s'_i) - adc_partner)
__global__ __launch_bounds__(1024) void finish_kernel(
    const float* __restrict__ cf, const float* __restrict__ s,
    float* __restrict__ out)
{
    __shared__ float red[16];
    int w    = threadIdx.x >> 6;
    int lane = threadIdx.x & 63;
    int i = blockIdx.x * 16 + w;
    int p = (i + BSZ) & (NROWS - 1);
    float2 x = *(const float2*)(cf + (size_t)i * DIM + lane * 2);
    float2 y = *(const float2*)(cf + (size_t)p * DIM + lane * 2);
    float d = x.x * y.x + x.y * y.y;
    #pragma unroll
    for (int m = 32; m >= 1; m >>= 1) d += __shfl_xor(d, m, 64);
    if (lane == 0) {
        float t2  = fmaxf(2.0f - 2.0f * d, EPSC);
        float adc = 1.0f - sqrtf(t2);
        red[w] = 1.0f + logf(s[i]) - adc;
    }
    __syncthreads();
    if (threadIdx.x == 0) {
        float acc = 0.f;
        #pragma unroll
        for (int k = 0; k < 16; ++k) acc += red[k];
        atomicAdd(out, acc * (1.0f / NROWS));
    }
}

extern "C" void kernel_launch(void* const* d_in, const int* in_sizes, int n_in,
                              void* d_out, int out_size, void* d_ws, size_t ws_size,
                              hipStream_t stream)
{
    const float* feat = (const float*)d_in[0];
    float* out = (float*)d_out;
    float* cf  = (float*)d_ws;                               // 4 MB fp32
    float* s   = cf + (size_t)NROWS * DIM;                   // 32 KB
    unsigned int* hsw = (unsigned int*)(s + NROWS);          // 2 MB fp16 (swizzled)

    norm_zero_kernel<<<(NROWS * 64) / 256, 256, 0, stream>>>(feat, cf, hsw, s, out);
    gram_tri_kernel<<<NTILES, 256, 0, stream>>>((const _Float16*)hsw, s);
    finish_kernel<<<NROWS / 16, 1024, 0, stream>>>(cf, s, out);
}